// Round 4
// baseline (287.734 us; speedup 1.0000x reference)
//
#include <hip/hip_runtime.h>
#include <hip/hip_bf16.h>

// LinearAttention: B=8, C=512, L=4096, HEADS=8, dim_head=64, hidden=512
// R9: gemm_kv reduction fixed: NO global atomics. Block = (n-chunk of 512, h, b)
//     runs 4 sub-tiles of 128; P@V^T accumulates in registers across sub-tiles;
//     row-sums accumulate in LDS. One plain store of the 64x64 partial per block
//     (8 slices per (b,h)); w2 sums slices. Zero-init pass deleted.
// Pipeline: prep_all; gemm_kv -> ctxp,Sp; w2(sum slices); W3=w2@Wq(gemm_bt); out=gemm_p(W3,xt).

typedef __bf16 bf16x8 __attribute__((ext_vector_type(8)));
typedef __bf16 bf16x4 __attribute__((ext_vector_type(4)));
typedef float  f32x4  __attribute__((ext_vector_type(4)));

#define B_  8
#define L_  4096
#define C_  512

#define GLD_LDS16(g, l)                                             \
    __builtin_amdgcn_global_load_lds(                               \
        (const __attribute__((address_space(1))) void*)(g),         \
        (__attribute__((address_space(3))) void*)(l), 16, 0, 0)

#define FENCE asm volatile("" ::: "memory")
#define BAR   do { FENCE; __builtin_amdgcn_s_barrier(); FENCE; } while (0)
#define DRAIN_LGKM asm volatile("s_waitcnt lgkmcnt(0)" ::: "memory")
#define WAIT_VM(N) asm volatile("s_waitcnt vmcnt(" #N ")" ::: "memory")

// ---------------- prep_all: x-transpose+cvt | wkv cvt | WqT ----------------
__global__ __launch_bounds__(256) void prep_all(const float* __restrict__ x,
                                                __hip_bfloat16* __restrict__ xt,
                                                const float* __restrict__ wqkv_f,
                                                __hip_bfloat16* __restrict__ wkv_b,
                                                __hip_bfloat16* __restrict__ wqT) {
    __shared__ float tile[64 * 132];
    int blk = blockIdx.x;
    int t = threadIdx.x;
    if (blk < 2048) {
        // transpose fp32 x[b][C][L] -> bf16 xt[b][L][C]; 64c x 128l tile
        int b = blk >> 8, rem = blk & 255;
        int l0 = (rem & 31) * 128, c0 = (rem >> 5) * 64;
        const float* xp = x + ((size_t)b * C_ + c0) * L_ + l0;
#pragma unroll
        for (int p = 0; p < 8; p++) {
            int i = p * 8 + (t >> 5);
            int j = (t & 31) * 4;
            float4 vv = *(const float4*)(xp + (size_t)i * L_ + j);
            *(float4*)&tile[i * 132 + j] = vv;
        }
        __syncthreads();
        unsigned short* xo = (unsigned short*)xt + ((size_t)b * L_ + l0) * C_ + c0;
#pragma unroll
        for (int qq = 0; qq < 8; qq++) {
            int l = qq * 16 + (t >> 4);
            int cg = (t & 15) * 4;
            bf16x4 ov;
#pragma unroll
            for (int k = 0; k < 4; k++) ov[k] = (__bf16)tile[(cg + k) * 132 + l];
            *(bf16x4*)(xo + (size_t)l * C_ + cg) = ov;
        }
    } else if (blk < 4096) {
        int i = (blk - 2048) * 256 + t;  // 1024*512 elements (w_qkv rows 512..1535)
        wkv_b[i] = __float2bfloat16(wqkv_f[512 * 512 + i]);
    } else {
        // wqT[c][c'] = w_qkv[c'][c] (q-part rows 0..511), bf16
        int tb = blk - 4096;
        int r0 = (tb >> 4) * 32, c0 = (tb & 15) * 32;
        int tx = t & 31, ty = t >> 5;
        for (int r = 0; r < 32; r += 8)
            tile[(ty + r) * 33 + tx] = wqkv_f[(size_t)(r0 + ty + r) * 512 + c0 + tx];
        __syncthreads();
        for (int r = 0; r < 32; r += 8)
            wqT[(size_t)(c0 + ty + r) * 512 + r0 + tx] = __float2bfloat16(tile[tx * 33 + ty + r]);
    }
}

// ---------------- fused kv-GEMM + softmax-context, register-accumulated ----------------
// Block (x=n-chunk (512 wide), y=head h, z=batch b). For each of 4 sub-tiles (128 n):
//   main 2-phase counted-vmcnt K-loop -> paired {k,v} 128x128 tile in acc;
//   tail: P=exp(k) (wv0/1, + LDS row-sum accum), V (wv2/3) -> dead sA/sB bf16
//   swizzled rows; 16-MFMA P@V^T accumulates acc2 ACROSS sub-tiles.
// End: plain store acc2 -> ctxp[slice][b*8+h][64][64], Sred -> Sp[slice][b*8+h][64].
__global__ __launch_bounds__(256, 2) void gemm_kv(
    const __hip_bfloat16* __restrict__ A, const __hip_bfloat16* __restrict__ Bt,
    float* __restrict__ ctxp, float* __restrict__ Sp) {
    __shared__ alignas(16) unsigned short sA[2][128 * 64];  // 32 KiB
    __shared__ alignas(16) unsigned short sB[2][128 * 64];  // 32 KiB
    __shared__ float Sred[64];

    const int K = C_;
    int b = blockIdx.z, h = blockIdx.y, slice = blockIdx.x;
    const __hip_bfloat16* Bb = Bt + (size_t)b * L_ * C_;

    int t = threadIdx.x;
    int lane = t & 63, wv = t >> 6;
    int l16 = lane & 15, q4 = lane >> 4;
    int wr = (wv >> 1) * 64, wc = (wv & 1) * 64;

    int srow = lane >> 3;
    int swz  = ((lane & 7) ^ srow) * 8;

    if (t < 64) Sred[t] = 0.f;

    const __hip_bfloat16* gA[4];
    unsigned ldoff[4];
    int rloc[4];
#pragma unroll
    for (int c = 0; c < 4; c++) {
        int r = c * 32 + wv * 8;
        int lr = r + srow;                             // local row 0..127
        int grow = h * 64 + lr + (lr >= 64 ? 448 : 0); // k rows / v rows of head h
        gA[c] = A + (size_t)grow * K + swz;
        ldoff[c] = (unsigned)r * 64;
        rloc[c] = lr;
    }

    int gsel0 = (q4 ^ (l16 & 7)) * 8;
    int gsel1 = gsel0 ^ 32;
    unsigned rA = (unsigned)(wr + l16) * 64;
    unsigned rB = (unsigned)(wc + l16) * 64;
    const int NKT = K >> 6;  // 8

    f32x4 acc2[4] = {};
    bf16x8 aF[4][2], bF[4][2];

#pragma unroll 1
    for (int sub = 0; sub < 4; ++sub) {
        int nt = slice * 512 + sub * 128;
        const __hip_bfloat16* gB[4];
#pragma unroll
        for (int c = 0; c < 4; c++)
            gB[c] = Bb + (size_t)(nt + rloc[c]) * K + swz;

        f32x4 acc[4][4] = {};

        // prologue: tile0 A+B, tile1 A; leave tile1 A (4) in flight
#pragma unroll
        for (int c = 0; c < 4; c++) GLD_LDS16(gA[c], &sA[0][ldoff[c]]);
#pragma unroll
        for (int c = 0; c < 4; c++) GLD_LDS16(gB[c], &sB[0][ldoff[c]]);
#pragma unroll
        for (int c = 0; c < 4; c++) GLD_LDS16(gA[c] + 64, &sA[1][ldoff[c]]);
        WAIT_VM(4);
        BAR;

#pragma unroll 1
        for (int kt = 0; kt < NKT; ++kt) {
            int cur = kt & 1, nbuf = cur ^ 1;
            const unsigned short* As_b = sA[cur];
            const unsigned short* Bs_b = sB[cur];
            bool st1 = (kt + 1) < NKT;
            bool st2 = (kt + 2) < NKT;

            // ---- phase 0: acc[0-3][0-1]; stage B(kt+1) -> other buf
#pragma unroll
            for (int i = 0; i < 4; i++) {
                aF[i][0] = *(const bf16x8*)&As_b[rA + i * 1024 + gsel0];
                aF[i][1] = *(const bf16x8*)&As_b[rA + i * 1024 + gsel1];
            }
#pragma unroll
            for (int j = 0; j < 2; j++) {
                bF[j][0] = *(const bf16x8*)&Bs_b[rB + j * 1024 + gsel0];
                bF[j][1] = *(const bf16x8*)&Bs_b[rB + j * 1024 + gsel1];
            }
            if (st1) {
                int ko = (kt + 1) << 6;
#pragma unroll
                for (int c = 0; c < 4; c++) GLD_LDS16(gB[c] + ko, &sB[nbuf][ldoff[c]]);
            }
            BAR;
            __builtin_amdgcn_s_setprio(1);
#pragma unroll
            for (int ks = 0; ks < 2; ks++)
#pragma unroll
                for (int i = 0; i < 4; i++)
#pragma unroll
                    for (int j = 0; j < 2; j++)
                        acc[i][j] = __builtin_amdgcn_mfma_f32_16x16x32_bf16(aF[i][ks], bF[j][ks], acc[i][j], 0, 0, 0);
            __builtin_amdgcn_s_setprio(0);
            DRAIN_LGKM;
            BAR;

            // ---- phase 1: acc[0-3][2-3]; stage A(kt+2) into SAME buffer
#pragma unroll
            for (int j = 2; j < 4; j++) {
                bF[j][0] = *(const bf16x8*)&Bs_b[rB + j * 1024 + gsel0];
                bF[j][1] = *(const bf16x8*)&Bs_b[rB + j * 1024 + gsel1];
            }
            if (st2) {
                int ko = (kt + 2) << 6;
#pragma unroll
                for (int c = 0; c < 4; c++) GLD_LDS16(gA[c] + ko, &sA[cur][ldoff[c]]);
            }
            BAR;
            __builtin_amdgcn_s_setprio(1);
#pragma unroll
            for (int ks = 0; ks < 2; ks++)
#pragma unroll
                for (int i = 0; i < 4; i++)
#pragma unroll
                    for (int j = 0; j < 2; j++)
                        acc[i][2 + j] = __builtin_amdgcn_mfma_f32_16x16x32_bf16(aF[i][ks], bF[2 + j][ks], acc[i][2 + j], 0, 0, 0);
            __builtin_amdgcn_s_setprio(0);
            DRAIN_LGKM;
            if (st2) { WAIT_VM(4); } else { WAIT_VM(0); }
            BAR;
        }
        // final BAR above: all staging + ds_reads done; sA/sB reusable for P/V.

        // ---- tail: P = exp(k) -> sA, V -> sB (bf16, 256B rows, group g^(row&15))
        __bf16* Pb = (__bf16*)sA;
        __bf16* Vb = (__bf16*)sB;

        if (wv < 2) {
#pragma unroll
            for (int i = 0; i < 4; i++)
#pragma unroll
                for (int r = 0; r < 4; r++) {
                    int d = i * 16 + q4 * 4 + r;
                    float rs = 0.f;
#pragma unroll
                    for (int j = 0; j < 4; j++) {
                        int n = wc + j * 16 + l16;
                        float pv = __expf(acc[i][j][r]);
                        rs += pv;
                        Pb[d * 128 + (((n >> 3) ^ (d & 15)) * 8) + (n & 7)] = (__bf16)pv;
                    }
                    rs += __shfl_xor(rs, 1, 64);
                    rs += __shfl_xor(rs, 2, 64);
                    rs += __shfl_xor(rs, 4, 64);
                    rs += __shfl_xor(rs, 8, 64);
                    if (l16 == 0) atomicAdd(&Sred[d], rs);  // LDS atomic, block-local
                }
        } else {
#pragma unroll
            for (int i = 0; i < 4; i++)
#pragma unroll
                for (int j = 0; j < 4; j++)
#pragma unroll
                    for (int r = 0; r < 4; r++) {
                        int e = i * 16 + q4 * 4 + r;
                        int n = wc + j * 16 + l16;
                        Vb[e * 128 + (((n >> 3) ^ (e & 15)) * 8) + (n & 7)] = (__bf16)acc[i][j][r];
                    }
        }
        DRAIN_LGKM;
        BAR;

        // ---- PV partial: acc2 += P(64x128) @ V^T; wave -> e in [wv*16,+16)
#pragma unroll
        for (int kk = 0; kk < 4; kk++) {
            int gg = kk * 4 + q4;
            bf16x8 bf2 = *(const bf16x8*)&Vb[(wv * 16 + l16) * 128 + ((gg ^ l16) * 8)];
#pragma unroll
            for (int i2 = 0; i2 < 4; i2++) {
                bf16x8 af2 = *(const bf16x8*)&Pb[(i2 * 16 + l16) * 128 + ((gg ^ l16) * 8)];
                acc2[i2] = __builtin_amdgcn_mfma_f32_16x16x32_bf16(af2, bf2, acc2[i2], 0, 0, 0);
            }
        }
        DRAIN_LGKM;
        BAR;  // P/V reads done before next sub overwrites sA/sB
    }

    // ---- epilogue: plain stores (no atomics)
    float* cg = ctxp + ((size_t)slice * 64 + b * 8 + h) * 4096;
#pragma unroll
    for (int i2 = 0; i2 < 4; i2++)
#pragma unroll
        for (int r = 0; r < 4; r++) {
            int d = i2 * 16 + q4 * 4 + r;
            int e = wv * 16 + l16;
            cg[d * 64 + e] = acc2[i2][r];
        }
    if (t < 64)
        Sp[((size_t)slice * 64 + b * 8 + h) * 64 + t] = Sred[t];
}

// ---------------- pipelined 128^2 GEMM (out = W3 @ x + bias), fp32 out ----------------
__global__ __launch_bounds__(256, 2) void gemm_p(
    const __hip_bfloat16* __restrict__ A, const __hip_bfloat16* __restrict__ Bt,
    size_t strideA, size_t strideB, int M, int N, int K,
    float* __restrict__ outb, const float* __restrict__ bias) {
    __shared__ alignas(16) unsigned short sA[2][128 * 64];
    __shared__ alignas(16) unsigned short sB[2][128 * 64];

    int b = blockIdx.z;
    int m0 = blockIdx.y * 128, n0 = blockIdx.x * 128;
    const __hip_bfloat16* Ab = A + strideA * (size_t)b;
    const __hip_bfloat16* Bb = Bt + strideB * (size_t)b;

    int t = threadIdx.x;
    int lane = t & 63, wv = t >> 6;
    int l16 = lane & 15, q4 = lane >> 4;
    int wr = (wv >> 1) * 64, wc = (wv & 1) * 64;

    int srow = lane >> 3;
    int swz  = ((lane & 7) ^ srow) * 8;

    const __hip_bfloat16* gA[4];
    const __hip_bfloat16* gB[4];
    unsigned ldoff[4];
#pragma unroll
    for (int c = 0; c < 4; c++) {
        int r = c * 32 + wv * 8;
        gA[c] = Ab + (size_t)(m0 + r + srow) * K + swz;
        gB[c] = Bb + (size_t)(n0 + r + srow) * K + swz;
        ldoff[c] = (unsigned)r * 64;
    }

    int gsel0 = (q4 ^ (l16 & 7)) * 8;
    int gsel1 = gsel0 ^ 32;
    unsigned rA = (unsigned)(wr + l16) * 64;
    unsigned rB = (unsigned)(wc + l16) * 64;
    int NKT = K >> 6;

    f32x4 acc[4][4] = {};
    bf16x8 aF[4][2], bF[4][2];

#pragma unroll
    for (int c = 0; c < 4; c++) GLD_LDS16(gA[c], &sA[0][ldoff[c]]);
#pragma unroll
    for (int c = 0; c < 4; c++) GLD_LDS16(gB[c], &sB[0][ldoff[c]]);
    if (NKT > 1) {
#pragma unroll
        for (int c = 0; c < 4; c++) GLD_LDS16(gA[c] + 64, &sA[1][ldoff[c]]);
        WAIT_VM(4);
    } else {
        WAIT_VM(0);
    }
    BAR;

#pragma unroll 1
    for (int kt = 0; kt < NKT; ++kt) {
        int cur = kt & 1, nbuf = cur ^ 1;
        const unsigned short* As_b = sA[cur];
        const unsigned short* Bs_b = sB[cur];
        bool st1 = (kt + 1) < NKT;
        bool st2 = (kt + 2) < NKT;

#pragma unroll
        for (int i = 0; i < 4; i++) {
            aF[i][0] = *(const bf16x8*)&As_b[rA + i * 1024 + gsel0];
            aF[i][1] = *(const bf16x8*)&As_b[rA + i * 1024 + gsel1];
        }
#pragma unroll
        for (int j = 0; j < 2; j++) {
            bF[j][0] = *(const bf16x8*)&Bs_b[rB + j * 1024 + gsel0];
            bF[j][1] = *(const bf16x8*)&Bs_b[rB + j * 1024 + gsel1];
        }
        if (st1) {
            int ko = (kt + 1) << 6;
#pragma unroll
            for (int c = 0; c < 4; c++) GLD_LDS16(gB[c] + ko, &sB[nbuf][ldoff[c]]);
        }
        BAR;
        __builtin_amdgcn_s_setprio(1);
#pragma unroll
        for (int ks = 0; ks < 2; ks++)
#pragma unroll
            for (int i = 0; i < 4; i++)
#pragma unroll
                for (int j = 0; j < 2; j++)
                    acc[i][j] = __builtin_amdgcn_mfma_f32_16x16x32_bf16(aF[i][ks], bF[j][ks], acc[i][j], 0, 0, 0);
        __builtin_amdgcn_s_setprio(0);
        DRAIN_LGKM;
        BAR;

#pragma unroll
        for (int j = 2; j < 4; j++) {
            bF[j][0] = *(const bf16x8*)&Bs_b[rB + j * 1024 + gsel0];
            bF[j][1] = *(const bf16x8*)&Bs_b[rB + j * 1024 + gsel1];
        }
        if (st2) {
            int ko = (kt + 2) << 6;
#pragma unroll
            for (int c = 0; c < 4; c++) GLD_LDS16(gA[c] + ko, &sA[cur][ldoff[c]]);
        }
        BAR;
        __builtin_amdgcn_s_setprio(1);
#pragma unroll
        for (int ks = 0; ks < 2; ks++)
#pragma unroll
            for (int i = 0; i < 4; i++)
#pragma unroll
                for (int j = 0; j < 2; j++)
                    acc[i][2 + j] = __builtin_amdgcn_mfma_f32_16x16x32_bf16(aF[i][ks], bF[2 + j][ks], acc[i][2 + j], 0, 0, 0);
        __builtin_amdgcn_s_setprio(0);
        DRAIN_LGKM;
        if (st2) { WAIT_VM(4); } else { WAIT_VM(0); }
        BAR;
    }

#pragma unroll
    for (int i = 0; i < 4; i++)
#pragma unroll
        for (int j = 0; j < 4; j++)
#pragma unroll
            for (int r = 0; r < 4; r++) {
                int row = m0 + wr + i * 16 + q4 * 4 + r;
                int col = n0 + wc + j * 16 + l16;
                outb[((size_t)b * M + row) * (size_t)N + col] = acc[i][j][r] + bias[row];
            }
}

// ---------------- 128^2 GEMM (small 512^3 GEMM), bf16 out ----------------
__global__ __launch_bounds__(256) void gemm_bt(
    const __hip_bfloat16* __restrict__ A, const __hip_bfloat16* __restrict__ Bt,
    size_t strideA, size_t strideB, int M, int N, int K,
    __hip_bfloat16* __restrict__ obf) {
    __shared__ alignas(16) unsigned short As[128 * 64];
    __shared__ alignas(16) unsigned short Bs[128 * 64];

    int b = blockIdx.z;
    int m0 = blockIdx.y * 128, n0 = blockIdx.x * 128;
    const __hip_bfloat16* Ab = A + strideA * (size_t)b;
    const __hip_bfloat16* Bb = Bt + strideB * (size_t)b;

    int t = threadIdx.x;
    int lane = t & 63, wv = t >> 6;
    int l16 = lane & 15, q4 = lane >> 4;
    int wr = (wv >> 1) * 64, wc = (wv & 1) * 64;

    int srow = lane >> 3;
    int swz  = ((lane & 7) ^ srow) * 8;

    const __hip_bfloat16* gA[4];
    const __hip_bfloat16* gB[4];
    unsigned short* lA[4];
    unsigned short* lB[4];
#pragma unroll
    for (int c = 0; c < 4; c++) {
        int r = wv * 32 + c * 8;
        gA[c] = Ab + (size_t)(m0 + r + srow) * K + swz;
        gB[c] = Bb + (size_t)(n0 + r + srow) * K + swz;
        lA[c] = &As[r * 64];
        lB[c] = &Bs[r * 64];
    }

    int gsel0 = ((q4) ^ (l16 & 7)) * 8;
    int gsel1 = gsel0 ^ 32;
    int rA = (wr + l16) * 64;
    int rB = (wc + l16) * 64;

    f32x4 acc[4][4] = {};

    for (int k0 = 0; k0 < K; k0 += 64) {
        __syncthreads();
#pragma unroll
        for (int c = 0; c < 4; c++) {
            GLD_LDS16(gA[c] + k0, lA[c]);
            GLD_LDS16(gB[c] + k0, lB[c]);
        }
        __syncthreads();

        bf16x8 af[4], bfr[4];
#pragma unroll
        for (int i = 0; i < 4; i++) {
            af[i]  = *(const bf16x8*)&As[rA + i * 1024 + gsel0];
            bfr[i] = *(const bf16x8*)&Bs[rB + i * 1024 + gsel0];
        }
#pragma unroll
        for (int i = 0; i < 4; i++)
#pragma unroll
            for (int j = 0; j < 4; j++)
                acc[i][j] = __builtin_amdgcn_mfma_f32_16x16x32_bf16(af[i], bfr[j], acc[i][j], 0, 0, 0);
#pragma unroll
        for (int i = 0; i < 4; i++) {
            af[i]  = *(const bf16x8*)&As[rA + i * 1024 + gsel1];
            bfr[i] = *(const bf16x8*)&Bs[rB + i * 1024 + gsel1];
        }
#pragma unroll
        for (int i = 0; i < 4; i++)
#pragma unroll
            for (int j = 0; j < 4; j++)
                acc[i][j] = __builtin_amdgcn_mfma_f32_16x16x32_bf16(af[i], bfr[j], acc[i][j], 0, 0, 0);
    }

#pragma unroll
    for (int i = 0; i < 4; i++)
#pragma unroll
        for (int j = 0; j < 4; j++)
#pragma unroll
            for (int r = 0; r < 4; r++) {
                int row = m0 + wr + i * 16 + q4 * 4 + r;
                int col = n0 + wc + j * 16 + l16;
                obf[((size_t)b * 512 + row) * (size_t)N + col] = __float2bfloat16(acc[i][j][r]);
            }
}

// ---------------- w2[b][o][h*64+d] = sum_e w_out[o][h*64+e] * ctx[d][e]/S[d] ----------------
__global__ __launch_bounds__(256) void w2_kernel(const float* __restrict__ wout,
                                                 const float* __restrict__ ctxp,
                                                 const float* __restrict__ Sp,
                                                 __hip_bfloat16* __restrict__ w2) {
    int ob = blockIdx.x, h = blockIdx.y, b = blockIdx.z;
    __shared__ float cT[64 * 65];  // [e][d], pre-scaled by 1/S[d]
    __shared__ float wT[64 * 65];  // [e][ol]
    __shared__ float Sinv[64];
    int t = threadIdx.x;
    const size_t SL = (size_t)64 * 4096;  // ctxp slice stride (floats)
    const float* cg = ctxp + ((size_t)b * 8 + h) * 4096;
    if (t < 64) {
        const float* sg = Sp + ((size_t)b * 8 + h) * 64;
        float S = 0.f;
#pragma unroll
        for (int s = 0; s < 8; s++) S += sg[(size_t)s * 64 * 64 + t];
        Sinv[t] = 1.0f / S;
    }
    __syncthreads();
    for (int i = t; i < 4096; i += 256) {
        int d = i >> 6, e = i & 63;
        float s = 0.f;
#pragma unroll
        for (int sl = 0; sl < 8; sl++) s += cg[(size_t)sl * SL + i];
        cT[e * 65 + d] = s * Sinv[d];
        wT[e * 65 + d] = wout[(size_t)(ob * 64 + d) * 512 + h * 64 + e];
    }
    __syncthreads();
    int ol = t >> 2;
    int db = (t & 3) * 16;
    unsigned short* w2p = (unsigned short*)w2 + ((size_t)b * 512 + ob * 64 + ol) * 512 + h * 64;
    for (int g = 0; g < 4; g++) {
        int d0 = db + g * 4;
        float s0 = 0.f, s1 = 0.f, s2 = 0.f, s3 = 0.f;
#pragma unroll
        for (int e = 0; e < 64; e++) {
            float w = wT[e * 65 + ol];
            s0 += w * cT[e * 65 + d0];
            s1 += w * cT[e * 65 + d0 + 1];
            s2 += w * cT[e * 65 + d0 + 2];
            s3 += w * cT[e * 65 + d0 + 3];
        }
        bf16x4 ov;
        ov[0] = (__bf16)s0; ov[1] = (__bf16)s1; ov[2] = (__bf16)s2; ov[3] = (__bf16)s3;
        *(bf16x4*)(w2p + d0) = ov;
    }
}

// ---------------- launch ----------------
extern "C" void kernel_launch(void* const* d_in, const int* in_sizes, int n_in,
                              void* d_out, int out_size, void* d_ws, size_t ws_size,
                              hipStream_t stream) {
    const float* x     = (const float*)d_in[0];
    const float* w_qkv = (const float*)d_in[1];
    const float* w_out = (const float*)d_in[2];
    const float* b_out = (const float*)d_in[3];
    float* out = (float*)d_out;
    char* ws = (char*)d_ws;

    size_t off_xt   = 0;                                      // bf16 [b][L][C]  32 MiB
    size_t off_wkv  = off_xt + (size_t)B_ * L_ * C_ * 2;      // bf16 1024x512    1 MiB
    size_t off_wqT  = off_wkv + (size_t)1024 * 512 * 2;       // bf16 512x512   0.5 MiB
    size_t off_ctxp = off_wqT + (size_t)512 * 512 * 2;        // fp32 8sl*64bh*4096  8 MiB
    size_t off_Sp   = off_ctxp + (size_t)8 * 64 * 4096 * 4;   // fp32 8sl*64bh*64  128 KiB
    size_t off_w2   = off_Sp + (size_t)8 * 64 * 64 * 4;       // bf16 8x512x512   4 MiB
    size_t off_w3   = off_w2 + (size_t)B_ * 512 * 512 * 2;    // bf16             4 MiB

    __hip_bfloat16* xt   = (__hip_bfloat16*)(ws + off_xt);
    __hip_bfloat16* wkvb = (__hip_bfloat16*)(ws + off_wkv);
    __hip_bfloat16* wqT  = (__hip_bfloat16*)(ws + off_wqT);
    float*          ctxp = (float*)(ws + off_ctxp);
    float*          Sp   = (float*)(ws + off_Sp);
    __hip_bfloat16* w2   = (__hip_bfloat16*)(ws + off_w2);
    __hip_bfloat16* W3   = (__hip_bfloat16*)(ws + off_w3);

    prep_all<<<4352, 256, 0, stream>>>(x, xt, w_qkv, wkvb, wqT);

    // fused: per (n-chunk 512, head, batch); K-loops + exp/rowsum + P@V^T partials
    gemm_kv<<<dim3(8, 8, B_), 256, 0, stream>>>(wkvb, xt, ctxp, Sp);

    w2_kernel<<<dim3(8, 8, B_), 256, 0, stream>>>(w_out, ctxp, Sp, w2);

    // W3[b] = w2[b] @ Wq   (M=512, N=512, K=512)
    gemm_bt<<<dim3(512 / 128, 512 / 128, B_), 256, 0, stream>>>(
        w2, wqT, (size_t)512 * 512, 0, 512, 512, 512, W3);

    // out = W3[b] @ x[b] + b_out   (M=512, N=4096, K=512)
    gemm_p<<<dim3(L_ / 128, 512 / 128, B_), 256, 0, stream>>>(
        W3, xt, (size_t)512 * 512, (size_t)L_ * C_, 512, L_, 512, out, b_out);
}

// Round 5
// 243.804 us; speedup vs baseline: 1.1802x; 1.1802x over previous
//
#include <hip/hip_runtime.h>
#include <hip/hip_bf16.h>

// LinearAttention: B=8, C=512, L=4096, HEADS=8, dim_head=64, hidden=512
// R10: revert to R7 structure (best, 244us), tail overhaul:
//  - gemm1 epilogue stores exp(k) (bf16) -> ctx loses all per-element exp/repack
//  - ctx: kc=8 (512 blocks, 2/CU), direct bf16x8 frag loads, rowsum adds,
//    per-slice partial stores (plumbing verified in R9); w2 sums 8 slices.
//  - prep transpose pad 132->133 (8-way -> 2-way LDS read conflicts)
//  - gemm3 uses the pipelined schedule (MODE 3)
// Pipeline: prep_all; gemm_p<1>(exp-k,v); ctx; w2; gemm_p<3>(W3); gemm_p<2>(out).

typedef __bf16 bf16x8 __attribute__((ext_vector_type(8)));
typedef __bf16 bf16x4 __attribute__((ext_vector_type(4)));
typedef float  f32x4  __attribute__((ext_vector_type(4)));

#define B_  8
#define L_  4096
#define C_  512

#define GLD_LDS16(g, l)                                             \
    __builtin_amdgcn_global_load_lds(                               \
        (const __attribute__((address_space(1))) void*)(g),         \
        (__attribute__((address_space(3))) void*)(l), 16, 0, 0)

#define FENCE asm volatile("" ::: "memory")
#define BAR   do { FENCE; __builtin_amdgcn_s_barrier(); FENCE; } while (0)
#define DRAIN_LGKM asm volatile("s_waitcnt lgkmcnt(0)" ::: "memory")
#define WAIT_VM(N) asm volatile("s_waitcnt vmcnt(" #N ")" ::: "memory")

// ---------------- prep_all: x-transpose+cvt | wkv cvt | WqT ----------------
__global__ __launch_bounds__(256) void prep_all(const float* __restrict__ x,
                                                __hip_bfloat16* __restrict__ xt,
                                                const float* __restrict__ wqkv_f,
                                                __hip_bfloat16* __restrict__ wkv_b,
                                                __hip_bfloat16* __restrict__ wqT) {
    __shared__ float tile[64 * 133];  // pad 133: read stride 532 % 32 = 20 -> 2-way (free)
    int blk = blockIdx.x;
    int t = threadIdx.x;
    if (blk < 2048) {
        // transpose fp32 x[b][C][L] -> bf16 xt[b][L][C]; 64c x 128l tile
        int b = blk >> 8, rem = blk & 255;
        int l0 = (rem & 31) * 128, c0 = (rem >> 5) * 64;
        const float* xp = x + ((size_t)b * C_ + c0) * L_ + l0;
#pragma unroll
        for (int p = 0; p < 8; p++) {
            int i = p * 8 + (t >> 5);
            int j = (t & 31) * 4;
            float4 vv = *(const float4*)(xp + (size_t)i * L_ + j);
            *(float4*)&tile[i * 133 + j] = vv;
        }
        __syncthreads();
        unsigned short* xo = (unsigned short*)xt + ((size_t)b * L_ + l0) * C_ + c0;
#pragma unroll
        for (int qq = 0; qq < 8; qq++) {
            int l = qq * 16 + (t >> 4);
            int cg = (t & 15) * 4;
            bf16x4 ov;
#pragma unroll
            for (int k = 0; k < 4; k++) ov[k] = (__bf16)tile[(cg + k) * 133 + l];
            *(bf16x4*)(xo + (size_t)l * C_ + cg) = ov;
        }
    } else if (blk < 4096) {
        int i = (blk - 2048) * 256 + t;  // 1024*512 elements (w_qkv rows 512..1535)
        wkv_b[i] = __float2bfloat16(wqkv_f[512 * 512 + i]);
    } else {
        // wqT[c][c'] = w_qkv[c'][c] (q-part rows 0..511), bf16
        int tb = blk - 4096;
        int r0 = (tb >> 4) * 32, c0 = (tb & 15) * 32;
        int tx = t & 31, ty = t >> 5;
        for (int r = 0; r < 32; r += 8)
            tile[(ty + r) * 33 + tx] = wqkv_f[(size_t)(r0 + ty + r) * 512 + c0 + tx];
        __syncthreads();
        for (int r = 0; r < 32; r += 8)
            wqT[(size_t)(c0 + ty + r) * 512 + r0 + tx] = __float2bfloat16(tile[tx * 33 + ty + r]);
    }
}

// ---------------- pipelined 128^2 GEMM, 2 blocks/CU ----------------
// C[M][N] = A[M][K] * Bt[N][K]^T.  BM=BN=128, BK=64, 2-phase counted-vmcnt
// schedule (R7, verified).  MODE 1: M=1024, rows 0-511 -> kb as exp(val) bf16,
// rows 512-1023 -> vb bf16.  MODE 2: fp32 out + bias.  MODE 3: bf16 out.
template <int MODE>
__global__ __launch_bounds__(256, 2) void gemm_p(
    const __hip_bfloat16* __restrict__ A, const __hip_bfloat16* __restrict__ Bt,
    size_t strideA, size_t strideB, int M, int N, int K,
    __hip_bfloat16* __restrict__ kb, __hip_bfloat16* __restrict__ vb,
    __hip_bfloat16* __restrict__ obf,
    float* __restrict__ outb, const float* __restrict__ bias) {
    __shared__ alignas(16) unsigned short sA[2][128 * 64];  // 32 KiB
    __shared__ alignas(16) unsigned short sB[2][128 * 64];  // 32 KiB

    int b = blockIdx.z;
    int m0 = blockIdx.y * 128, n0 = blockIdx.x * 128;
    const __hip_bfloat16* Ab = A + strideA * (size_t)b;
    const __hip_bfloat16* Bb = Bt + strideB * (size_t)b;

    int t = threadIdx.x;
    int lane = t & 63, wv = t >> 6;
    int l16 = lane & 15, q4 = lane >> 4;
    int wr = (wv >> 1) * 64, wc = (wv & 1) * 64;

    int srow = lane >> 3;
    int swz  = ((lane & 7) ^ srow) * 8;

    const __hip_bfloat16* gA[4];
    const __hip_bfloat16* gB[4];
    unsigned ldoff[4];
#pragma unroll
    for (int c = 0; c < 4; c++) {
        int r = c * 32 + wv * 8;
        gA[c] = Ab + (size_t)(m0 + r + srow) * K + swz;
        gB[c] = Bb + (size_t)(n0 + r + srow) * K + swz;
        ldoff[c] = (unsigned)r * 64;
    }

    int gsel0 = (q4 ^ (l16 & 7)) * 8;
    int gsel1 = gsel0 ^ 32;
    unsigned rA = (unsigned)(wr + l16) * 64;
    unsigned rB = (unsigned)(wc + l16) * 64;
    int NKT = K >> 6;

    f32x4 acc[4][4] = {};
    bf16x8 aF[4][2], bF[4][2];

    // prologue: tile0 A+B, tile1 A; leave tile1 A (4) in flight
#pragma unroll
    for (int c = 0; c < 4; c++) GLD_LDS16(gA[c], &sA[0][ldoff[c]]);
#pragma unroll
    for (int c = 0; c < 4; c++) GLD_LDS16(gB[c], &sB[0][ldoff[c]]);
    if (NKT > 1) {
#pragma unroll
        for (int c = 0; c < 4; c++) GLD_LDS16(gA[c] + 64, &sA[1][ldoff[c]]);
        WAIT_VM(4);
    } else {
        WAIT_VM(0);
    }
    BAR;

#pragma unroll 1
    for (int kt = 0; kt < NKT; ++kt) {
        int cur = kt & 1, nbuf = cur ^ 1;
        const unsigned short* As_b = sA[cur];
        const unsigned short* Bs_b = sB[cur];
        bool st1 = (kt + 1) < NKT;
        bool st2 = (kt + 2) < NKT;

        // ---- phase 0: acc[0-3][0-1]; stage B(kt+1) -> other buf
#pragma unroll
        for (int i = 0; i < 4; i++) {
            aF[i][0] = *(const bf16x8*)&As_b[rA + i * 1024 + gsel0];
            aF[i][1] = *(const bf16x8*)&As_b[rA + i * 1024 + gsel1];
        }
#pragma unroll
        for (int j = 0; j < 2; j++) {
            bF[j][0] = *(const bf16x8*)&Bs_b[rB + j * 1024 + gsel0];
            bF[j][1] = *(const bf16x8*)&Bs_b[rB + j * 1024 + gsel1];
        }
        if (st1) {
            int ko = (kt + 1) << 6;
#pragma unroll
            for (int c = 0; c < 4; c++) GLD_LDS16(gB[c] + ko, &sB[nbuf][ldoff[c]]);
        }
        BAR;
        __builtin_amdgcn_s_setprio(1);
#pragma unroll
        for (int ks = 0; ks < 2; ks++)
#pragma unroll
            for (int i = 0; i < 4; i++)
#pragma unroll
                for (int j = 0; j < 2; j++)
                    acc[i][j] = __builtin_amdgcn_mfma_f32_16x16x32_bf16(aF[i][ks], bF[j][ks], acc[i][j], 0, 0, 0);
        __builtin_amdgcn_s_setprio(0);
        DRAIN_LGKM;
        BAR;

        // ---- phase 1: acc[0-3][2-3]; stage A(kt+2) into SAME buffer
#pragma unroll
        for (int j = 2; j < 4; j++) {
            bF[j][0] = *(const bf16x8*)&Bs_b[rB + j * 1024 + gsel0];
            bF[j][1] = *(const bf16x8*)&Bs_b[rB + j * 1024 + gsel1];
        }
        if (st2) {
            int ko = (kt + 2) << 6;
#pragma unroll
            for (int c = 0; c < 4; c++) GLD_LDS16(gA[c] + ko, &sA[cur][ldoff[c]]);
        }
        BAR;
        __builtin_amdgcn_s_setprio(1);
#pragma unroll
        for (int ks = 0; ks < 2; ks++)
#pragma unroll
            for (int i = 0; i < 4; i++)
#pragma unroll
                for (int j = 0; j < 2; j++)
                    acc[i][2 + j] = __builtin_amdgcn_mfma_f32_16x16x32_bf16(aF[i][ks], bF[2 + j][ks], acc[i][2 + j], 0, 0, 0);
        __builtin_amdgcn_s_setprio(0);
        DRAIN_LGKM;
        if (st2) { WAIT_VM(4); } else { WAIT_VM(0); }
        BAR;
    }

    // epilogue: D row = q4*4 + r (within 16), col = l16
#pragma unroll
    for (int i = 0; i < 4; i++)
#pragma unroll
        for (int j = 0; j < 4; j++)
#pragma unroll
            for (int r = 0; r < 4; r++) {
                int row = m0 + wr + i * 16 + q4 * 4 + r;
                int col = n0 + wc + j * 16 + l16;
                float val = acc[i][j][r];
                if (MODE == 1) {
                    bool isk = (m0 < 512);  // 128-tile never straddles k/v halves
                    __hip_bfloat16* dst = isk ? kb : vb;
                    if (isk) val = __expf(val);  // store exp(k): ctx needs only exp
                    dst[((size_t)b * 512 + (row & 511)) * (size_t)N + col] = __float2bfloat16(val);
                } else if (MODE == 3) {
                    obf[((size_t)b * 512 + row) * (size_t)N + col] = __float2bfloat16(val);
                } else {
                    outb[((size_t)b * M + row) * (size_t)N + col] = val + bias[row];
                }
            }
}

// ---------------- ctx partials: ctxp[kc][bh][d][e] = sum_{n in kc} ek[d,n]*v[e,n]
//                  Sp[kc][bh][d] = sum_{n in kc} ek[d,n]   (ek = exp(k), precomputed)
__global__ __launch_bounds__(256) void ctx_kernel(const __hip_bfloat16* __restrict__ ek,
                                                  const __hip_bfloat16* __restrict__ v,
                                                  float* __restrict__ ctxp,
                                                  float* __restrict__ Sp) {
    int kc = blockIdx.x, h = blockIdx.y, b = blockIdx.z;  // kc 0..7 (512 cols each)
    int t = threadIdx.x, lane = t & 63, wv = t >> 6;
    int l16 = lane & 15, q4 = lane >> 4;
    const __hip_bfloat16* ka = ek + ((size_t)b * 512 + h * 64) * L_;
    const __hip_bfloat16* va = v + ((size_t)b * 512 + h * 64) * L_;

    f32x4 acc[4][4] = {};
    float ps[4] = {0.f, 0.f, 0.f, 0.f};
    int nbase = kc * 512 + wv * 128;
#pragma unroll
    for (int s = 0; s < 4; s++) {
        int n = nbase + s * 32 + q4 * 8;
        bf16x8 af[4], bfr[4];
#pragma unroll
        for (int i = 0; i < 4; i++) {
            af[i]  = *(const bf16x8*)(ka + (size_t)(i * 16 + l16) * L_ + n);
            bfr[i] = *(const bf16x8*)(va + (size_t)(i * 16 + l16) * L_ + n);
#pragma unroll
            for (int e = 0; e < 8; e++) ps[i] += (float)af[i][e];
        }
#pragma unroll
        for (int i = 0; i < 4; i++)
#pragma unroll
            for (int j = 0; j < 4; j++)
                acc[i][j] = __builtin_amdgcn_mfma_f32_16x16x32_bf16(af[i], bfr[j], acc[i][j], 0, 0, 0);
    }

    // row-sum reduce: over q4 (lanes ^16, ^32), then across waves via LDS
    __shared__ float sred[4][64];
#pragma unroll
    for (int i = 0; i < 4; i++) {
        ps[i] += __shfl_xor(ps[i], 16, 64);
        ps[i] += __shfl_xor(ps[i], 32, 64);
    }
    if (q4 == 0) {
#pragma unroll
        for (int i = 0; i < 4; i++) sred[wv][i * 16 + l16] = ps[i];
    }

    // merge 4 waves' acc into cbuf (serial rounds), then plain store
    __shared__ float cbuf[4096];
    __syncthreads();
    for (int w = 0; w < 4; w++) {
        if (wv == w) {
#pragma unroll
            for (int i = 0; i < 4; i++)
#pragma unroll
                for (int j = 0; j < 4; j++)
#pragma unroll
                    for (int r = 0; r < 4; r++) {
                        int mm = i * 16 + q4 * 4 + r, nn = j * 16 + l16;
                        float pv = acc[i][j][r];
                        if (w == 0) cbuf[mm * 64 + nn] = pv;
                        else        cbuf[mm * 64 + nn] += pv;
                    }
        }
        __syncthreads();
    }
    float* cg = ctxp + ((size_t)kc * 64 + b * 8 + h) * 4096;
    for (int i = t; i < 4096; i += 256) cg[i] = cbuf[i];
    if (t < 64)
        Sp[((size_t)kc * 64 + b * 8 + h) * 64 + t] = sred[0][t] + sred[1][t] + sred[2][t] + sred[3][t];
}

// ---------------- w2[b][o][h*64+d] = sum_e w_out[o][h*64+e] * ctx[d][e]/S[d] ----------------
__global__ __launch_bounds__(256) void w2_kernel(const float* __restrict__ wout,
                                                 const float* __restrict__ ctxp,
                                                 const float* __restrict__ Sp,
                                                 __hip_bfloat16* __restrict__ w2) {
    int ob = blockIdx.x, h = blockIdx.y, b = blockIdx.z;
    __shared__ float cT[64 * 65];  // [e][d], pre-scaled by 1/S[d]
    __shared__ float wT[64 * 65];  // [e][ol]
    __shared__ float Sinv[64];
    int t = threadIdx.x;
    const size_t SL = (size_t)64 * 4096;  // ctxp slice stride (floats)
    const float* cg = ctxp + ((size_t)b * 8 + h) * 4096;
    if (t < 64) {
        const float* sg = Sp + ((size_t)b * 8 + h) * 64;
        float S = 0.f;
#pragma unroll
        for (int s = 0; s < 8; s++) S += sg[(size_t)s * 64 * 64 + t];
        Sinv[t] = 1.0f / S;
    }
    __syncthreads();
    for (int i = t; i < 4096; i += 256) {
        int d = i >> 6, e = i & 63;
        float s = 0.f;
#pragma unroll
        for (int sl = 0; sl < 8; sl++) s += cg[(size_t)sl * SL + i];
        cT[e * 65 + d] = s * Sinv[d];
        wT[e * 65 + d] = wout[(size_t)(ob * 64 + d) * 512 + h * 64 + e];
    }
    __syncthreads();
    int ol = t >> 2;
    int db = (t & 3) * 16;
    unsigned short* w2p = (unsigned short*)w2 + ((size_t)b * 512 + ob * 64 + ol) * 512 + h * 64;
    for (int g = 0; g < 4; g++) {
        int d0 = db + g * 4;
        float s0 = 0.f, s1 = 0.f, s2 = 0.f, s3 = 0.f;
#pragma unroll
        for (int e = 0; e < 64; e++) {
            float w = wT[e * 65 + ol];
            s0 += w * cT[e * 65 + d0];
            s1 += w * cT[e * 65 + d0 + 1];
            s2 += w * cT[e * 65 + d0 + 2];
            s3 += w * cT[e * 65 + d0 + 3];
        }
        bf16x4 ov;
        ov[0] = (__bf16)s0; ov[1] = (__bf16)s1; ov[2] = (__bf16)s2; ov[3] = (__bf16)s3;
        *(bf16x4*)(w2p + d0) = ov;
    }
}

// ---------------- launch ----------------
extern "C" void kernel_launch(void* const* d_in, const int* in_sizes, int n_in,
                              void* d_out, int out_size, void* d_ws, size_t ws_size,
                              hipStream_t stream) {
    const float* x     = (const float*)d_in[0];
    const float* w_qkv = (const float*)d_in[1];
    const float* w_out = (const float*)d_in[2];
    const float* b_out = (const float*)d_in[3];
    float* out = (float*)d_out;
    char* ws = (char*)d_ws;

    const size_t QKV = (size_t)B_ * 512 * L_;
    size_t off_xt   = 0;                                      // bf16 [b][L][C]  32 MiB
    size_t off_wkv  = off_xt + (size_t)B_ * L_ * C_ * 2;      // bf16 1024x512    1 MiB
    size_t off_wqT  = off_wkv + (size_t)1024 * 512 * 2;       // bf16 512x512   0.5 MiB
    size_t off_k    = off_wqT + (size_t)512 * 512 * 2;        // bf16 exp(k)     32 MiB
    size_t off_v    = off_k + QKV * 2;                        // bf16            32 MiB
    size_t off_ctxp = off_v + QKV * 2;                        // fp32 8sl*64bh*4096 8 MiB
    size_t off_Sp   = off_ctxp + (size_t)8 * 64 * 4096 * 4;   // fp32 8sl*64bh*64 128 KiB
    // w2 / W3 overlay the dead kb region (kb fully consumed by ctx before w2 writes)
    size_t off_w2   = off_k;                                  // bf16 8x512x512   4 MiB
    size_t off_w3   = off_k + (size_t)B_ * 512 * 512 * 2;     // bf16             4 MiB

    __hip_bfloat16* xt   = (__hip_bfloat16*)(ws + off_xt);
    __hip_bfloat16* wkvb = (__hip_bfloat16*)(ws + off_wkv);
    __hip_bfloat16* wqT  = (__hip_bfloat16*)(ws + off_wqT);
    __hip_bfloat16* kb   = (__hip_bfloat16*)(ws + off_k);
    __hip_bfloat16* vb   = (__hip_bfloat16*)(ws + off_v);
    float*          ctxp = (float*)(ws + off_ctxp);
    float*          Sp   = (float*)(ws + off_Sp);
    __hip_bfloat16* w2   = (__hip_bfloat16*)(ws + off_w2);
    __hip_bfloat16* W3   = (__hip_bfloat16*)(ws + off_w3);

    prep_all<<<4352, 256, 0, stream>>>(x, xt, w_qkv, wkvb, wqT);

    // ek,v = Wkv @ x  (M=1024, N=4096, K=512 per batch); k stored as exp(k)
    gemm_p<1><<<dim3(L_ / 128, 1024 / 128, B_), 256, 0, stream>>>(
        wkvb, xt, 0, (size_t)L_ * C_, 1024, L_, 512, kb, vb, nullptr, nullptr, nullptr);

    // ctx partials + row sums (kc = 8, 512 blocks)
    ctx_kernel<<<dim3(8, 8, B_), 256, 0, stream>>>(kb, vb, ctxp, Sp);

    w2_kernel<<<dim3(8, 8, B_), 256, 0, stream>>>(w_out, ctxp, Sp, w2);

    // W3[b] = w2[b] @ Wq   (M=512, N=512, K=512) — pipelined, bf16 out
    gemm_p<3><<<dim3(512 / 128, 512 / 128, B_), 256, 0, stream>>>(
        w2, wqT, (size_t)512 * 512, 0, 512, 512, 512, nullptr, nullptr, W3, nullptr, nullptr);

    // out = W3[b] @ x[b] + b_out   (M=512, N=4096, K=512)
    gemm_p<2><<<dim3(L_ / 128, 512 / 128, B_), 256, 0, stream>>>(
        W3, xt, (size_t)512 * 512, (size_t)L_ * C_, 512, L_, 512, nullptr, nullptr, nullptr, out, b_out);
}

// Round 6
// 243.585 us; speedup vs baseline: 1.1812x; 1.0009x over previous
//
#include <hip/hip_runtime.h>
#include <hip/hip_bf16.h>

// LinearAttention: B=8, C=512, L=4096, HEADS=8, dim_head=64, hidden=512
// R11: tail tuning (GEMMs untouched at the measured 48us wall):
//  - prep: xt stores widened to bf16x8 (16B/lane); 2-way-free LDS reads
//  - ctx: d-split -> 1024 blocks (2x occupancy), same ctxp/Sp layout
//  - w2: float4 slice-sum + float4 wout loads
// Pipeline: prep_all; gemm_p<1>(exp-k,v); ctx; w2; gemm_p<3>(W3); gemm_p<2>(out).

typedef __bf16 bf16x8 __attribute__((ext_vector_type(8)));
typedef __bf16 bf16x4 __attribute__((ext_vector_type(4)));
typedef float  f32x4  __attribute__((ext_vector_type(4)));

#define B_  8
#define L_  4096
#define C_  512

#define GLD_LDS16(g, l)                                             \
    __builtin_amdgcn_global_load_lds(                               \
        (const __attribute__((address_space(1))) void*)(g),         \
        (__attribute__((address_space(3))) void*)(l), 16, 0, 0)

#define FENCE asm volatile("" ::: "memory")
#define BAR   do { FENCE; __builtin_amdgcn_s_barrier(); FENCE; } while (0)
#define DRAIN_LGKM asm volatile("s_waitcnt lgkmcnt(0)" ::: "memory")
#define WAIT_VM(N) asm volatile("s_waitcnt vmcnt(" #N ")" ::: "memory")

// ---------------- prep_all: x-transpose+cvt | wkv cvt | WqT ----------------
__global__ __launch_bounds__(256) void prep_all(const float* __restrict__ x,
                                                __hip_bfloat16* __restrict__ xt,
                                                const float* __restrict__ wqkv_f,
                                                __hip_bfloat16* __restrict__ wkv_b,
                                                __hip_bfloat16* __restrict__ wqT) {
    __shared__ float tile[64 * 133];
    int blk = blockIdx.x;
    int t = threadIdx.x;
    if (blk < 2048) {
        // transpose fp32 x[b][C][L] -> bf16 xt[b][L][C]; 64c x 128l tile
        int b = blk >> 8, rem = blk & 255;
        int l0 = (rem & 31) * 128, c0 = (rem >> 5) * 64;
        const float* xp = x + ((size_t)b * C_ + c0) * L_ + l0;
#pragma unroll
        for (int p = 0; p < 8; p++) {
            int i = p * 8 + (t >> 5);
            int j = (t & 31) * 4;
            float4 vv = *(const float4*)(xp + (size_t)i * L_ + j);
            *(float4*)&tile[i * 133 + j] = vv;
        }
        __syncthreads();
        // store: thread -> (l = qq*32 + t>>3, c-group (t&7)*8); 16 B/lane stores.
        // LDS read bank = (8*(t&7) + 5k + (t>>3)) % 32 -> exactly 2 lanes/bank (free).
        unsigned short* xo = (unsigned short*)xt + ((size_t)b * L_ + l0) * C_ + c0;
        int cg8 = (t & 7) * 8;
#pragma unroll
        for (int qq = 0; qq < 4; qq++) {
            int l = qq * 32 + (t >> 3);
            bf16x8 ov;
#pragma unroll
            for (int k = 0; k < 8; k++) ov[k] = (__bf16)tile[(cg8 + k) * 133 + l];
            *(bf16x8*)(xo + (size_t)l * C_ + cg8) = ov;
        }
    } else if (blk < 4096) {
        int i = (blk - 2048) * 256 + t;  // 1024*512 elements (w_qkv rows 512..1535)
        wkv_b[i] = __float2bfloat16(wqkv_f[512 * 512 + i]);
    } else {
        // wqT[c][c'] = w_qkv[c'][c] (q-part rows 0..511), bf16
        int tb = blk - 4096;
        int r0 = (tb >> 4) * 32, c0 = (tb & 15) * 32;
        int tx = t & 31, ty = t >> 5;
        for (int r = 0; r < 32; r += 8)
            tile[(ty + r) * 33 + tx] = wqkv_f[(size_t)(r0 + ty + r) * 512 + c0 + tx];
        __syncthreads();
        for (int r = 0; r < 32; r += 8)
            wqT[(size_t)(c0 + ty + r) * 512 + r0 + tx] = __float2bfloat16(tile[tx * 33 + ty + r]);
    }
}

// ---------------- pipelined 128^2 GEMM, 2 blocks/CU ----------------
// C[M][N] = A[M][K] * Bt[N][K]^T.  BM=BN=128, BK=64, 2-phase counted-vmcnt
// schedule (R7, verified).  MODE 1: M=1024, rows 0-511 -> kb as exp(val) bf16,
// rows 512-1023 -> vb bf16.  MODE 2: fp32 out + bias.  MODE 3: bf16 out.
template <int MODE>
__global__ __launch_bounds__(256, 2) void gemm_p(
    const __hip_bfloat16* __restrict__ A, const __hip_bfloat16* __restrict__ Bt,
    size_t strideA, size_t strideB, int M, int N, int K,
    __hip_bfloat16* __restrict__ kb, __hip_bfloat16* __restrict__ vb,
    __hip_bfloat16* __restrict__ obf,
    float* __restrict__ outb, const float* __restrict__ bias) {
    __shared__ alignas(16) unsigned short sA[2][128 * 64];  // 32 KiB
    __shared__ alignas(16) unsigned short sB[2][128 * 64];  // 32 KiB

    int b = blockIdx.z;
    int m0 = blockIdx.y * 128, n0 = blockIdx.x * 128;
    const __hip_bfloat16* Ab = A + strideA * (size_t)b;
    const __hip_bfloat16* Bb = Bt + strideB * (size_t)b;

    int t = threadIdx.x;
    int lane = t & 63, wv = t >> 6;
    int l16 = lane & 15, q4 = lane >> 4;
    int wr = (wv >> 1) * 64, wc = (wv & 1) * 64;

    int srow = lane >> 3;
    int swz  = ((lane & 7) ^ srow) * 8;

    const __hip_bfloat16* gA[4];
    const __hip_bfloat16* gB[4];
    unsigned ldoff[4];
#pragma unroll
    for (int c = 0; c < 4; c++) {
        int r = c * 32 + wv * 8;
        gA[c] = Ab + (size_t)(m0 + r + srow) * K + swz;
        gB[c] = Bb + (size_t)(n0 + r + srow) * K + swz;
        ldoff[c] = (unsigned)r * 64;
    }

    int gsel0 = (q4 ^ (l16 & 7)) * 8;
    int gsel1 = gsel0 ^ 32;
    unsigned rA = (unsigned)(wr + l16) * 64;
    unsigned rB = (unsigned)(wc + l16) * 64;
    int NKT = K >> 6;

    f32x4 acc[4][4] = {};
    bf16x8 aF[4][2], bF[4][2];

    // prologue: tile0 A+B, tile1 A; leave tile1 A (4) in flight
#pragma unroll
    for (int c = 0; c < 4; c++) GLD_LDS16(gA[c], &sA[0][ldoff[c]]);
#pragma unroll
    for (int c = 0; c < 4; c++) GLD_LDS16(gB[c], &sB[0][ldoff[c]]);
    if (NKT > 1) {
#pragma unroll
        for (int c = 0; c < 4; c++) GLD_LDS16(gA[c] + 64, &sA[1][ldoff[c]]);
        WAIT_VM(4);
    } else {
        WAIT_VM(0);
    }
    BAR;

#pragma unroll 1
    for (int kt = 0; kt < NKT; ++kt) {
        int cur = kt & 1, nbuf = cur ^ 1;
        const unsigned short* As_b = sA[cur];
        const unsigned short* Bs_b = sB[cur];
        bool st1 = (kt + 1) < NKT;
        bool st2 = (kt + 2) < NKT;

        // ---- phase 0: acc[0-3][0-1]; stage B(kt+1) -> other buf
#pragma unroll
        for (int i = 0; i < 4; i++) {
            aF[i][0] = *(const bf16x8*)&As_b[rA + i * 1024 + gsel0];
            aF[i][1] = *(const bf16x8*)&As_b[rA + i * 1024 + gsel1];
        }
#pragma unroll
        for (int j = 0; j < 2; j++) {
            bF[j][0] = *(const bf16x8*)&Bs_b[rB + j * 1024 + gsel0];
            bF[j][1] = *(const bf16x8*)&Bs_b[rB + j * 1024 + gsel1];
        }
        if (st1) {
            int ko = (kt + 1) << 6;
#pragma unroll
            for (int c = 0; c < 4; c++) GLD_LDS16(gB[c] + ko, &sB[nbuf][ldoff[c]]);
        }
        BAR;
        __builtin_amdgcn_s_setprio(1);
#pragma unroll
        for (int ks = 0; ks < 2; ks++)
#pragma unroll
            for (int i = 0; i < 4; i++)
#pragma unroll
                for (int j = 0; j < 2; j++)
                    acc[i][j] = __builtin_amdgcn_mfma_f32_16x16x32_bf16(aF[i][ks], bF[j][ks], acc[i][j], 0, 0, 0);
        __builtin_amdgcn_s_setprio(0);
        DRAIN_LGKM;
        BAR;

        // ---- phase 1: acc[0-3][2-3]; stage A(kt+2) into SAME buffer
#pragma unroll
        for (int j = 2; j < 4; j++) {
            bF[j][0] = *(const bf16x8*)&Bs_b[rB + j * 1024 + gsel0];
            bF[j][1] = *(const bf16x8*)&Bs_b[rB + j * 1024 + gsel1];
        }
        if (st2) {
            int ko = (kt + 2) << 6;
#pragma unroll
            for (int c = 0; c < 4; c++) GLD_LDS16(gA[c] + ko, &sA[cur][ldoff[c]]);
        }
        BAR;
        __builtin_amdgcn_s_setprio(1);
#pragma unroll
        for (int ks = 0; ks < 2; ks++)
#pragma unroll
            for (int i = 0; i < 4; i++)
#pragma unroll
                for (int j = 0; j < 2; j++)
                    acc[i][2 + j] = __builtin_amdgcn_mfma_f32_16x16x32_bf16(aF[i][ks], bF[2 + j][ks], acc[i][2 + j], 0, 0, 0);
        __builtin_amdgcn_s_setprio(0);
        DRAIN_LGKM;
        if (st2) { WAIT_VM(4); } else { WAIT_VM(0); }
        BAR;
    }

    // epilogue: D row = q4*4 + r (within 16), col = l16
#pragma unroll
    for (int i = 0; i < 4; i++)
#pragma unroll
        for (int j = 0; j < 4; j++)
#pragma unroll
            for (int r = 0; r < 4; r++) {
                int row = m0 + wr + i * 16 + q4 * 4 + r;
                int col = n0 + wc + j * 16 + l16;
                float val = acc[i][j][r];
                if (MODE == 1) {
                    bool isk = (m0 < 512);  // 128-tile never straddles k/v halves
                    __hip_bfloat16* dst = isk ? kb : vb;
                    if (isk) val = __expf(val);  // store exp(k): ctx needs only exp
                    dst[((size_t)b * 512 + (row & 511)) * (size_t)N + col] = __float2bfloat16(val);
                } else if (MODE == 3) {
                    obf[((size_t)b * 512 + row) * (size_t)N + col] = __float2bfloat16(val);
                } else {
                    outb[((size_t)b * M + row) * (size_t)N + col] = val + bias[row];
                }
            }
}

// ---------------- ctx partials: ctxp[kc][bh][d][e] = sum_{n in kc} ek[d,n]*v[e,n]
//                  Sp[kc][bh][d] = sum ek[d,n].  d split across 2 blocks (dh) for
//                  occupancy: grid (16 = kc*2+dh, 8 h, 8 b) = 1024 blocks.
__global__ __launch_bounds__(256) void ctx_kernel(const __hip_bfloat16* __restrict__ ek,
                                                  const __hip_bfloat16* __restrict__ v,
                                                  float* __restrict__ ctxp,
                                                  float* __restrict__ Sp) {
    int bx = blockIdx.x;
    int kc = bx >> 1, dh = bx & 1;
    int h = blockIdx.y, b = blockIdx.z;
    int t = threadIdx.x, lane = t & 63, wv = t >> 6;
    int l16 = lane & 15, q4 = lane >> 4;
    const __hip_bfloat16* ka = ek + ((size_t)b * 512 + h * 64 + dh * 32) * L_;
    const __hip_bfloat16* va = v + ((size_t)b * 512 + h * 64) * L_;

    f32x4 acc[2][4] = {};
    float ps[2] = {0.f, 0.f};
    int nbase = kc * 512 + wv * 128;
#pragma unroll
    for (int s = 0; s < 4; s++) {
        int n = nbase + s * 32 + q4 * 8;
        bf16x8 af[2], bfr[4];
#pragma unroll
        for (int i = 0; i < 2; i++) {
            af[i] = *(const bf16x8*)(ka + (size_t)(i * 16 + l16) * L_ + n);
#pragma unroll
            for (int e = 0; e < 8; e++) ps[i] += (float)af[i][e];
        }
#pragma unroll
        for (int j = 0; j < 4; j++)
            bfr[j] = *(const bf16x8*)(va + (size_t)(j * 16 + l16) * L_ + n);
#pragma unroll
        for (int i = 0; i < 2; i++)
#pragma unroll
            for (int j = 0; j < 4; j++)
                acc[i][j] = __builtin_amdgcn_mfma_f32_16x16x32_bf16(af[i], bfr[j], acc[i][j], 0, 0, 0);
    }

    // row-sum reduce: over q4 (lanes ^16, ^32), then across waves via LDS
    __shared__ float sred[4][32];
#pragma unroll
    for (int i = 0; i < 2; i++) {
        ps[i] += __shfl_xor(ps[i], 16, 64);
        ps[i] += __shfl_xor(ps[i], 32, 64);
    }
    if (q4 == 0) {
#pragma unroll
        for (int i = 0; i < 2; i++) sred[wv][i * 16 + l16] = ps[i];
    }

    // merge 4 waves' acc into cbuf (serial rounds), then plain store
    __shared__ float cbuf[2048];
    __syncthreads();
    for (int w = 0; w < 4; w++) {
        if (wv == w) {
#pragma unroll
            for (int i = 0; i < 2; i++)
#pragma unroll
                for (int j = 0; j < 4; j++)
#pragma unroll
                    for (int r = 0; r < 4; r++) {
                        int mm = i * 16 + q4 * 4 + r, nn = j * 16 + l16;
                        float pv = acc[i][j][r];
                        if (w == 0) cbuf[mm * 64 + nn] = pv;
                        else        cbuf[mm * 64 + nn] += pv;
                    }
        }
        __syncthreads();
    }
    float* cg = ctxp + ((size_t)kc * 64 + b * 8 + h) * 4096 + dh * 2048;
    for (int i = t; i < 2048; i += 256) cg[i] = cbuf[i];
    if (t < 32)
        Sp[((size_t)kc * 64 + b * 8 + h) * 64 + dh * 32 + t] =
            sred[0][t] + sred[1][t] + sred[2][t] + sred[3][t];
}

// ---------------- w2[b][o][h*64+d] = sum_e w_out[o][h*64+e] * ctx[d][e]/S[d] ----------------
__global__ __launch_bounds__(256) void w2_kernel(const float* __restrict__ wout,
                                                 const float* __restrict__ ctxp,
                                                 const float* __restrict__ Sp,
                                                 __hip_bfloat16* __restrict__ w2) {
    int ob = blockIdx.x, h = blockIdx.y, b = blockIdx.z;
    __shared__ float cT[64 * 65];  // [e][d], pre-scaled by 1/S[d]
    __shared__ float wT[64 * 65];  // [e][ol]
    __shared__ float Sinv[64];
    int t = threadIdx.x;
    const size_t SL = (size_t)64 * 4096;  // ctxp slice stride (floats)
    const float* cg = ctxp + ((size_t)b * 8 + h) * 4096;
    if (t < 64) {
        const float* sg = Sp + ((size_t)b * 8 + h) * 64;
        float S = 0.f;
#pragma unroll
        for (int s = 0; s < 8; s++) S += sg[(size_t)s * 64 * 64 + t];
        Sinv[t] = 1.0f / S;
    }
    __syncthreads();
#pragma unroll
    for (int it = 0; it < 4; ++it) {
        int i0 = (t + it * 256) * 4;
        int d = i0 >> 6, e0 = i0 & 63;
        float4 s4 = {0.f, 0.f, 0.f, 0.f};
#pragma unroll
        for (int sl = 0; sl < 8; sl++) {
            float4 vv = *(const float4*)&cg[(size_t)sl * SL + i0];
            s4.x += vv.x; s4.y += vv.y; s4.z += vv.z; s4.w += vv.w;
        }
        float si = Sinv[d];
        float4 wv4 = *(const float4*)&wout[(size_t)(ob * 64 + d) * 512 + h * 64 + e0];
        cT[(e0 + 0) * 65 + d] = s4.x * si;
        cT[(e0 + 1) * 65 + d] = s4.y * si;
        cT[(e0 + 2) * 65 + d] = s4.z * si;
        cT[(e0 + 3) * 65 + d] = s4.w * si;
        wT[(e0 + 0) * 65 + d] = wv4.x;
        wT[(e0 + 1) * 65 + d] = wv4.y;
        wT[(e0 + 2) * 65 + d] = wv4.z;
        wT[(e0 + 3) * 65 + d] = wv4.w;
    }
    __syncthreads();
    int ol = t >> 2;
    int db = (t & 3) * 16;
    unsigned short* w2p = (unsigned short*)w2 + ((size_t)b * 512 + ob * 64 + ol) * 512 + h * 64;
    for (int g = 0; g < 4; g++) {
        int d0 = db + g * 4;
        float s0 = 0.f, s1 = 0.f, s2 = 0.f, s3 = 0.f;
#pragma unroll
        for (int e = 0; e < 64; e++) {
            float w = wT[e * 65 + ol];
            s0 += w * cT[e * 65 + d0];
            s1 += w * cT[e * 65 + d0 + 1];
            s2 += w * cT[e * 65 + d0 + 2];
            s3 += w * cT[e * 65 + d0 + 3];
        }
        bf16x4 ov;
        ov[0] = (__bf16)s0; ov[1] = (__bf16)s1; ov[2] = (__bf16)s2; ov[3] = (__bf16)s3;
        *(bf16x4*)(w2p + d0) = ov;
    }
}

// ---------------- launch ----------------
extern "C" void kernel_launch(void* const* d_in, const int* in_sizes, int n_in,
                              void* d_out, int out_size, void* d_ws, size_t ws_size,
                              hipStream_t stream) {
    const float* x     = (const float*)d_in[0];
    const float* w_qkv = (const float*)d_in[1];
    const float* w_out = (const float*)d_in[2];
    const float* b_out = (const float*)d_in[3];
    float* out = (float*)d_out;
    char* ws = (char*)d_ws;

    const size_t QKV = (size_t)B_ * 512 * L_;
    size_t off_xt   = 0;                                      // bf16 [b][L][C]  32 MiB
    size_t off_wkv  = off_xt + (size_t)B_ * L_ * C_ * 2;      // bf16 1024x512    1 MiB
    size_t off_wqT  = off_wkv + (size_t)1024 * 512 * 2;       // bf16 512x512   0.5 MiB
    size_t off_k    = off_wqT + (size_t)512 * 512 * 2;        // bf16 exp(k)     32 MiB
    size_t off_v    = off_k + QKV * 2;                        // bf16            32 MiB
    size_t off_ctxp = off_v + QKV * 2;                        // fp32 8sl*64bh*4096 8 MiB
    size_t off_Sp   = off_ctxp + (size_t)8 * 64 * 4096 * 4;   // fp32 8sl*64bh*64 128 KiB
    // w2 / W3 overlay the dead kb region (kb fully consumed by ctx before w2 writes)
    size_t off_w2   = off_k;                                  // bf16 8x512x512   4 MiB
    size_t off_w3   = off_k + (size_t)B_ * 512 * 512 * 2;     // bf16             4 MiB

    __hip_bfloat16* xt   = (__hip_bfloat16*)(ws + off_xt);
    __hip_bfloat16* wkvb = (__hip_bfloat16*)(ws + off_wkv);
    __hip_bfloat16* wqT  = (__hip_bfloat16*)(ws + off_wqT);
    __hip_bfloat16* kb   = (__hip_bfloat16*)(ws + off_k);
    __hip_bfloat16* vb   = (__hip_bfloat16*)(ws + off_v);
    float*          ctxp = (float*)(ws + off_ctxp);
    float*          Sp   = (float*)(ws + off_Sp);
    __hip_bfloat16* w2   = (__hip_bfloat16*)(ws + off_w2);
    __hip_bfloat16* W3   = (__hip_bfloat16*)(ws + off_w3);

    prep_all<<<4352, 256, 0, stream>>>(x, xt, w_qkv, wkvb, wqT);

    // ek,v = Wkv @ x  (M=1024, N=4096, K=512 per batch); k stored as exp(k)
    gemm_p<1><<<dim3(L_ / 128, 1024 / 128, B_), 256, 0, stream>>>(
        wkvb, xt, 0, (size_t)L_ * C_, 1024, L_, 512, kb, vb, nullptr, nullptr, nullptr);

    // ctx partials + row sums (kc=8 x dh=2, 1024 blocks)
    ctx_kernel<<<dim3(16, 8, B_), 256, 0, stream>>>(kb, vb, ctxp, Sp);

    w2_kernel<<<dim3(8, 8, B_), 256, 0, stream>>>(w_out, ctxp, Sp, w2);

    // W3[b] = w2[b] @ Wq   (M=512, N=512, K=512) — pipelined, bf16 out
    gemm_p<3><<<dim3(512 / 128, 512 / 128, B_), 256, 0, stream>>>(
        w2, wqT, (size_t)512 * 512, 0, 512, 512, 512, nullptr, nullptr, W3, nullptr, nullptr);

    // out = W3[b] @ x[b] + b_out   (M=512, N=4096, K=512)
    gemm_p<2><<<dim3(L_ / 128, 512 / 128, B_), 256, 0, stream>>>(
        W3, xt, (size_t)512 * 512, (size_t)L_ * C_, 512, L_, 512, nullptr, nullptr, nullptr, out, b_out);
}